// Round 3
// baseline (865.972 us; speedup 1.0000x reference)
//
#include <hip/hip_runtime.h>
#include <hip/hip_bf16.h>

// B=4, S=8192 -> 32768 tokens; HID=1024; NH=DH=32.
// S1q: q=(query@Wq^T+bq)/32 -> bf16 @ dout_b[tok*2048 + n]
// S1k: k=(key@Wk^T+bk)      -> bf16 @ dout_b[tok*2048 + 1024 + n]
// S2 : per-token 32x32 scores + softmax over heads-t -> p (bf16 in d_ws if it
//      fits, else f32 in-place in d_out)
// S3 : v GEMM; epilogue out[idx] = p[idx] * (v+bv)
//
// GEMM: 128x128 tile, BK=32, 4 waves (64x64 each). bf16 LDS, subtiled
// conflict-free layout [row/16][kslot][row%16][16B]; reg-staged f32->bf16
// (T14 async split: loads issued before compute, cvt+ds_write after barrier).

typedef __attribute__((ext_vector_type(8))) short bf16x8;
typedef __attribute__((ext_vector_type(4))) float f32x4;

#define HID 1024

__device__ __forceinline__ unsigned short f2bf(float f) {
  unsigned int u = __builtin_bit_cast(unsigned int, f);
  u += 0x7FFFu + ((u >> 16) & 1u);  // RTNE
  return (unsigned short)(u >> 16);
}
__device__ __forceinline__ float bf2f(unsigned short h) {
  unsigned int u = (unsigned int)h << 16;
  return __builtin_bit_cast(float, u);
}

// 8 consecutive f32 (two 16B regs) -> bf16x8 via v_cvt_pk_bf16_f32
__device__ __forceinline__ bf16x8 cvt8(f32x4 a, f32x4 b) {
  union { unsigned int u[4]; bf16x8 v; } r;
  asm("v_cvt_pk_bf16_f32 %0, %1, %2" : "=v"(r.u[0]) : "v"(a[0]), "v"(a[1]));
  asm("v_cvt_pk_bf16_f32 %0, %1, %2" : "=v"(r.u[1]) : "v"(a[2]), "v"(a[3]));
  asm("v_cvt_pk_bf16_f32 %0, %1, %2" : "=v"(r.u[2]) : "v"(b[0]), "v"(b[1]));
  asm("v_cvt_pk_bf16_f32 %0, %1, %2" : "=v"(r.u[3]) : "v"(b[2]), "v"(b[3]));
  return r.v;
}

// out[m,n] = sum_k X[m,k]*W[n,k] + b[n]
template<int MODE>
__global__ __launch_bounds__(256, 2)
void gemm_kernel(const float* __restrict__ X, const float* __restrict__ W,
                 const float* __restrict__ bias, void* outp,
                 const unsigned short* __restrict__ pbf, int use_ws) {
  // XCD-chunked bijective swizzle: 2048 blocks = 8 chunks x 256; n fastest.
  const int bid = blockIdx.x;
  const int L = (bid & 7) * 256 + (bid >> 3);
  const int m0 = (L >> 3) * 128;
  const int n0 = (L & 7) * 128;
  const int tid = threadIdx.x;
  const int lane = tid & 63;
  const int wid = tid >> 6;
  const int wm = (wid >> 1) << 6;
  const int wn = (wid & 1) << 6;
  const int lo = lane & 15, grp = lane >> 4;

  // per buffer: A bf16 subtiled 8KB @0, B 8KB @8192. addr(row,slot) =
  // (row>>4)*1024 + slot*256 + (row&15)*16, slot = k/8.
  __shared__ __align__(16) unsigned char lds[2][16384];

  // staging: thread -> (row = tid&127, slots {sgrp, sgrp+2})
  const int srow = tid & 127;
  const int sgrp = tid >> 7;
  const float* Ag = X + (size_t)(m0 + srow) * HID + sgrp * 8;
  const float* Bg = W + (size_t)(n0 + srow) * HID + sgrp * 8;
  const int wb = (srow >> 4) * 1024 + (srow & 15) * 16;

  f32x4 la[4], lb[4];
  auto gload = [&](int k0) {
    la[0] = *(const f32x4*)(Ag + k0);
    la[1] = *(const f32x4*)(Ag + k0 + 4);
    la[2] = *(const f32x4*)(Ag + k0 + 16);
    la[3] = *(const f32x4*)(Ag + k0 + 20);
    lb[0] = *(const f32x4*)(Bg + k0);
    lb[1] = *(const f32x4*)(Bg + k0 + 4);
    lb[2] = *(const f32x4*)(Bg + k0 + 16);
    lb[3] = *(const f32x4*)(Bg + k0 + 20);
  };
  auto cvtwrite = [&](int b) {
    *(bf16x8*)&lds[b][wb + sgrp * 256]              = cvt8(la[0], la[1]);
    *(bf16x8*)&lds[b][wb + (sgrp + 2) * 256]        = cvt8(la[2], la[3]);
    *(bf16x8*)&lds[b][8192 + wb + sgrp * 256]       = cvt8(lb[0], lb[1]);
    *(bf16x8*)&lds[b][8192 + wb + (sgrp + 2) * 256] = cvt8(lb[2], lb[3]);
  };

  f32x4 acc[4][4] = {};
  const int rbA = ((wm >> 4)) * 1024 + grp * 256 + lo * 16;
  const int rbB = 8192 + ((wn >> 4)) * 1024 + grp * 256 + lo * 16;
  auto compute = [&](int b) {
    bf16x8 af[4], bfm[4];
#pragma unroll
    for (int f = 0; f < 4; ++f) {
      af[f]  = *(const bf16x8*)&lds[b][rbA + f * 1024];
      bfm[f] = *(const bf16x8*)&lds[b][rbB + f * 1024];
    }
#pragma unroll
    for (int fm = 0; fm < 4; ++fm)
#pragma unroll
      for (int fn = 0; fn < 4; ++fn)
        acc[fm][fn] = __builtin_amdgcn_mfma_f32_16x16x32_bf16(
            af[fm], bfm[fn], acc[fm][fn], 0, 0, 0);
  };

  gload(0);
  cvtwrite(0);
  __syncthreads();
#pragma unroll 1
  for (int kt = 0; kt < 32; ++kt) {
    if (kt + 1 < 32) gload((kt + 1) * 32);     // issue early (T14)
    compute(kt & 1);
    __syncthreads();
    if (kt + 1 < 32) {
      cvtwrite((kt + 1) & 1);                  // vmcnt wait inserted here
      __syncthreads();
    }
  }

  // Epilogue. C layout: col=lane&15, row=(lane>>4)*4+j (m89-verified).
  unsigned char* eb = &lds[0][0];  // 32KB staging
  if (MODE == 2) {
    float* of = (float*)outp;
#pragma unroll
    for (int fm = 0; fm < 4; ++fm) {
      const int row = m0 + wm + fm * 16 + grp * 4;
#pragma unroll
      for (int fn = 0; fn < 4; ++fn) {
        const int col = n0 + wn + fn * 16 + lo;
        const float bc = bias[col];
#pragma unroll
        for (int j = 0; j < 4; ++j) {
          const size_t idx = (size_t)(row + j) * 1024 + col;
          const float p = use_ws ? bf2f(pbf[idx]) : of[idx];
          of[idx] = p * (acc[fm][fn][j] + bc);
        }
      }
    }
  } else {
    const float scale = (MODE == 0) ? 0.03125f : 1.0f;
#pragma unroll
    for (int fm = 0; fm < 4; ++fm) {
#pragma unroll
      for (int fn = 0; fn < 4; ++fn) {
        const int colL = wn + fn * 16 + lo;
        const float bc = bias[n0 + colL];
#pragma unroll
        for (int j = 0; j < 4; ++j) {
          const int rowL = wm + fm * 16 + grp * 4 + j;
          const int byte = rowL * 256 + ((colL * 2) ^ ((rowL & 7) << 5));
          *(unsigned short*)&eb[byte] = f2bf((acc[fm][fn][j] + bc) * scale);
        }
      }
    }
    __syncthreads();
    unsigned short* ob = (unsigned short*)outp;
    const int half = (MODE == 1) ? 1024 : 0;
#pragma unroll
    for (int p = 0; p < 8; ++p) {
      const int r = p * 16 + (tid >> 4);
      const int c0 = (tid & 15) * 8;
      const uint4 v = *(const uint4*)&eb[r * 256 + ((c0 * 2) ^ ((r & 7) << 5))];
      *(uint4*)&ob[(size_t)(m0 + r) * 2048 + half + n0 + c0] = v;
    }
  }
}

// S2: one wave per token. 32x32 scores via 4 MFMA, softmax over t (cols).
// PMODE 0: write f32 p in-place over the token's q/k region in d_out.
// PMODE 1: write bf16 p to d_ws[tok*1024 + h*32 + t].
template<int PMODE>
__global__ __launch_bounds__(256)
void attn_kernel(float* __restrict__ dout, unsigned short* __restrict__ wsp) {
  const int wid = threadIdx.x >> 6;
  const int lane = threadIdx.x & 63;
  const int token = blockIdx.x * 4 + wid;
  const int lo = lane & 15, grp = lane >> 4;
  const unsigned short* qk = (const unsigned short*)dout + (size_t)token * 2048;
  const int base = lo * 32 + grp * 8;

  bf16x8 a0 = *(const bf16x8*)(qk + base);
  bf16x8 a1 = *(const bf16x8*)(qk + 512 + base);
  bf16x8 b0 = *(const bf16x8*)(qk + 1024 + base);
  bf16x8 b1 = *(const bf16x8*)(qk + 1536 + base);
  asm volatile("s_waitcnt vmcnt(0)" ::: "memory");  // before in-place overwrite

  const f32x4 z = {0.f, 0.f, 0.f, 0.f};
  f32x4 s[2][2];
  s[0][0] = __builtin_amdgcn_mfma_f32_16x16x32_bf16(a0, b0, z, 0, 0, 0);
  s[0][1] = __builtin_amdgcn_mfma_f32_16x16x32_bf16(a0, b1, z, 0, 0, 0);
  s[1][0] = __builtin_amdgcn_mfma_f32_16x16x32_bf16(a1, b0, z, 0, 0, 0);
  s[1][1] = __builtin_amdgcn_mfma_f32_16x16x32_bf16(a1, b1, z, 0, 0, 0);

  float* od = dout + (size_t)token * 1024;
  unsigned short* ob = wsp + (size_t)token * 1024;
#pragma unroll
  for (int rt = 0; rt < 2; ++rt) {
#pragma unroll
    for (int j = 0; j < 4; ++j) {
      const float v0 = s[rt][0][j], v1 = s[rt][1][j];
      float m = fmaxf(v0, v1);
#pragma unroll
      for (int msk = 1; msk < 16; msk <<= 1) m = fmaxf(m, __shfl_xor(m, msk, 64));
      const float e0 = __expf(v0 - m), e1 = __expf(v1 - m);
      float ssum = e0 + e1;
#pragma unroll
      for (int msk = 1; msk < 16; msk <<= 1) ssum += __shfl_xor(ssum, msk, 64);
      const float inv = 1.0f / ssum;
      const int h = rt * 16 + grp * 4 + j;
      if (PMODE == 0) {
        od[h * 32 + lo]      = e0 * inv;
        od[h * 32 + 16 + lo] = e1 * inv;
      } else {
        ob[h * 32 + lo]      = f2bf(e0 * inv);
        ob[h * 32 + 16 + lo] = f2bf(e1 * inv);
      }
    }
  }
}

extern "C" void kernel_launch(void* const* d_in, const int* in_sizes, int n_in,
                              void* d_out, int out_size, void* d_ws, size_t ws_size,
                              hipStream_t stream) {
  const float* query = (const float*)d_in[0];
  const float* key   = (const float*)d_in[1];
  const float* value = (const float*)d_in[2];
  const float* Wq    = (const float*)d_in[3];
  const float* bq    = (const float*)d_in[4];
  const float* Wk    = (const float*)d_in[5];
  const float* bk    = (const float*)d_in[6];
  const float* Wv    = (const float*)d_in[7];
  const float* bv    = (const float*)d_in[8];

  const int use_ws = (ws_size >= (size_t)32768 * 1024 * 2) ? 1 : 0;
  unsigned short* pbf = (unsigned short*)d_ws;

  gemm_kernel<0><<<dim3(2048), dim3(256), 0, stream>>>(query, Wq, bq, d_out, nullptr, 0);
  gemm_kernel<1><<<dim3(2048), dim3(256), 0, stream>>>(key,   Wk, bk, d_out, nullptr, 0);
  if (use_ws)
    attn_kernel<1><<<dim3(8192), dim3(256), 0, stream>>>((float*)d_out, pbf);
  else
    attn_kernel<0><<<dim3(8192), dim3(256), 0, stream>>>((float*)d_out, nullptr);
  gemm_kernel<2><<<dim3(2048), dim3(256), 0, stream>>>(value, Wv, bv, d_out, pbf, use_ws);
}

// Round 4
// 860.082 us; speedup vs baseline: 1.0068x; 1.0068x over previous
//
#include <hip/hip_runtime.h>
#include <hip/hip_bf16.h>

// B=4, S=8192 -> 32768 tokens; HID=1024; NH=DH=32.
// S1q: q=(query@Wq^T+bq)/32 -> bf16 @ dout_b[tok*2048 + n]
// S1k: k=(key@Wk^T+bk)      -> bf16 @ dout_b[tok*2048 + 1024 + n]
// S2 : per-token 32x32 scores + softmax over heads-t -> p (bf16 in d_ws if it
//      fits, else f32 in-place in d_out)
// S3 : v GEMM; epilogue out[idx] = p[idx] * (v+bv)
//
// GEMM: 128x128 tile, BK=32, 4 waves (64x64). bf16 LDS, subtiled
// conflict-free layout [row/16][kslot][row%16][16B] (r3: 0 bank conflicts).
// Pipeline: single raw s_barrier per K-step (lgkmcnt drain only — global
// loads stay in flight across it); loads issued 1 full phase before use.

typedef __attribute__((ext_vector_type(8))) short bf16x8;
typedef __attribute__((ext_vector_type(4))) float f32x4;

#define HID 1024

__device__ __forceinline__ unsigned short f2bf(float f) {
  unsigned int u = __builtin_bit_cast(unsigned int, f);
  u += 0x7FFFu + ((u >> 16) & 1u);  // RTNE
  return (unsigned short)(u >> 16);
}
__device__ __forceinline__ float bf2f(unsigned short h) {
  unsigned int u = (unsigned int)h << 16;
  return __builtin_bit_cast(float, u);
}

// 8 consecutive f32 (two 16B regs) -> bf16x8 via v_cvt_pk_bf16_f32
__device__ __forceinline__ bf16x8 cvt8(f32x4 a, f32x4 b) {
  union { unsigned int u[4]; bf16x8 v; } r;
  asm("v_cvt_pk_bf16_f32 %0, %1, %2" : "=v"(r.u[0]) : "v"(a[0]), "v"(a[1]));
  asm("v_cvt_pk_bf16_f32 %0, %1, %2" : "=v"(r.u[1]) : "v"(a[2]), "v"(a[3]));
  asm("v_cvt_pk_bf16_f32 %0, %1, %2" : "=v"(r.u[2]) : "v"(b[0]), "v"(b[1]));
  asm("v_cvt_pk_bf16_f32 %0, %1, %2" : "=v"(r.u[3]) : "v"(b[2]), "v"(b[3]));
  return r.v;
}

// out[m,n] = sum_k X[m,k]*W[n,k] + b[n]
template<int MODE>
__global__ __launch_bounds__(256, 2)
void gemm_kernel(const float* __restrict__ X, const float* __restrict__ W,
                 const float* __restrict__ bias, void* outp,
                 const unsigned short* __restrict__ pbf, int use_ws) {
  // XCD-chunked bijective swizzle: 2048 blocks = 8 chunks x 256; n fastest.
  const int bid = blockIdx.x;
  const int L = (bid & 7) * 256 + (bid >> 3);
  const int m0 = (L >> 3) * 128;
  const int n0 = (L & 7) * 128;
  const int tid = threadIdx.x;
  const int lane = tid & 63;
  const int wid = tid >> 6;
  const int wm = (wid >> 1) << 6;
  const int wn = (wid & 1) << 6;
  const int lo = lane & 15, grp = lane >> 4;

  // per buffer: A bf16 subtiled 8KB @0, B 8KB @8192.
  // addr(row, kslot) = (row>>4)*1024 + kslot*256 + (row&15)*16, kslot=k/8.
  __shared__ __align__(16) unsigned char lds[2][16384];

  // staging: thread -> row = tid&127, kslots {sgrp, sgrp+2}, sgrp = tid>>7
  const int srow = tid & 127;
  const int sgrp = tid >> 7;
  const float* Ag = X + (size_t)(m0 + srow) * HID + sgrp * 8;
  const float* Bg = W + (size_t)(n0 + srow) * HID + sgrp * 8;
  const int wb = (srow >> 4) * 1024 + (srow & 15) * 16;

  f32x4 la[4], lb[4];
  auto gload = [&](int k0) {
    la[0] = *(const f32x4*)(Ag + k0);
    la[1] = *(const f32x4*)(Ag + k0 + 4);
    la[2] = *(const f32x4*)(Ag + k0 + 16);
    la[3] = *(const f32x4*)(Ag + k0 + 20);
    lb[0] = *(const f32x4*)(Bg + k0);
    lb[1] = *(const f32x4*)(Bg + k0 + 4);
    lb[2] = *(const f32x4*)(Bg + k0 + 16);
    lb[3] = *(const f32x4*)(Bg + k0 + 20);
  };
  auto cvtwrite = [&](int b) {
    *(bf16x8*)&lds[b][wb + sgrp * 256]              = cvt8(la[0], la[1]);
    *(bf16x8*)&lds[b][wb + (sgrp + 2) * 256]        = cvt8(la[2], la[3]);
    *(bf16x8*)&lds[b][8192 + wb + sgrp * 256]       = cvt8(lb[0], lb[1]);
    *(bf16x8*)&lds[b][8192 + wb + (sgrp + 2) * 256] = cvt8(lb[2], lb[3]);
  };

  f32x4 acc[4][4] = {};
  const int rbA = (wm >> 4) * 1024 + grp * 256 + lo * 16;
  const int rbB = 8192 + (wn >> 4) * 1024 + grp * 256 + lo * 16;
  auto compute = [&](int b) {
    bf16x8 af[4], bfm[4];
#pragma unroll
    for (int f = 0; f < 4; ++f) {
      af[f]  = *(const bf16x8*)&lds[b][rbA + f * 1024];
      bfm[f] = *(const bf16x8*)&lds[b][rbB + f * 1024];
    }
#pragma unroll
    for (int fm = 0; fm < 4; ++fm)
#pragma unroll
      for (int fn = 0; fn < 4; ++fn)
        acc[fm][fn] = __builtin_amdgcn_mfma_f32_16x16x32_bf16(
            af[fm], bfm[fn], acc[fm][fn], 0, 0, 0);
  };

  // Prologue: tile0 staged (cold vmcnt wait once), tile1 left in flight.
  gload(0);
  cvtwrite(0);
  gload(32);
  __builtin_amdgcn_sched_barrier(0);
  asm volatile("s_waitcnt lgkmcnt(0)" ::: "memory");
  __builtin_amdgcn_s_barrier();
  __builtin_amdgcn_sched_barrier(0);

#pragma unroll 1
  for (int kt = 0; kt < 32; ++kt) {
    compute(kt & 1);                       // ds_read + MFMA on current buffer
    if (kt < 31) {
      cvtwrite((kt + 1) & 1);              // vmcnt wait lands HERE (1 phase late)
      if (kt < 30) gload((kt + 2) * 32);   // issue next; in flight across barrier
    }
    __builtin_amdgcn_sched_barrier(0);
    asm volatile("s_waitcnt lgkmcnt(0)" ::: "memory");  // ds ops drained only
    __builtin_amdgcn_s_barrier();          // raw: vmem loads NOT drained
    __builtin_amdgcn_sched_barrier(0);
  }

  // Epilogue. C layout: col=lane&15, row=(lane>>4)*4+j (m89-verified).
  unsigned char* eb = &lds[0][0];  // 32KB staging
  if (MODE == 2) {
    float* of = (float*)outp;
#pragma unroll
    for (int fm = 0; fm < 4; ++fm) {
      const int row = m0 + wm + fm * 16 + grp * 4;
#pragma unroll
      for (int fn = 0; fn < 4; ++fn) {
        const int col = n0 + wn + fn * 16 + lo;
        const float bc = bias[col];
#pragma unroll
        for (int j = 0; j < 4; ++j) {
          const size_t idx = (size_t)(row + j) * 1024 + col;
          const float p = use_ws ? bf2f(pbf[idx]) : of[idx];
          of[idx] = p * (acc[fm][fn][j] + bc);
        }
      }
    }
  } else {
    const float scale = (MODE == 0) ? 0.03125f : 1.0f;
#pragma unroll
    for (int fm = 0; fm < 4; ++fm) {
#pragma unroll
      for (int fn = 0; fn < 4; ++fn) {
        const int colL = wn + fn * 16 + lo;
        const float bc = bias[n0 + colL];
#pragma unroll
        for (int j = 0; j < 4; ++j) {
          const int rowL = wm + fm * 16 + grp * 4 + j;
          const int byte = rowL * 256 + ((colL * 2) ^ ((rowL & 7) << 5));
          *(unsigned short*)&eb[byte] = f2bf((acc[fm][fn][j] + bc) * scale);
        }
      }
    }
    __syncthreads();
    unsigned short* ob = (unsigned short*)outp;
    const int half = (MODE == 1) ? 1024 : 0;
#pragma unroll
    for (int p = 0; p < 8; ++p) {
      const int r = p * 16 + (tid >> 4);
      const int c0 = (tid & 15) * 8;
      const uint4 v = *(const uint4*)&eb[r * 256 + ((c0 * 2) ^ ((r & 7) << 5))];
      *(uint4*)&ob[(size_t)(m0 + r) * 2048 + half + n0 + c0] = v;
    }
  }
}

// S2: one wave per token. 32x32 scores via 4 MFMA, softmax over t (cols).
// PMODE 0: write f32 p in-place over the token's q/k region in d_out.
// PMODE 1: write bf16 p to d_ws[tok*1024 + h*32 + t].
template<int PMODE>
__global__ __launch_bounds__(256)
void attn_kernel(float* __restrict__ dout, unsigned short* __restrict__ wsp) {
  const int wid = threadIdx.x >> 6;
  const int lane = threadIdx.x & 63;
  const int token = blockIdx.x * 4 + wid;
  const int lo = lane & 15, grp = lane >> 4;
  const unsigned short* qk = (const unsigned short*)dout + (size_t)token * 2048;
  const int base = lo * 32 + grp * 8;

  bf16x8 a0 = *(const bf16x8*)(qk + base);
  bf16x8 a1 = *(const bf16x8*)(qk + 512 + base);
  bf16x8 b0 = *(const bf16x8*)(qk + 1024 + base);
  bf16x8 b1 = *(const bf16x8*)(qk + 1536 + base);
  asm volatile("s_waitcnt vmcnt(0)" ::: "memory");  // before in-place overwrite

  const f32x4 z = {0.f, 0.f, 0.f, 0.f};
  f32x4 s[2][2];
  s[0][0] = __builtin_amdgcn_mfma_f32_16x16x32_bf16(a0, b0, z, 0, 0, 0);
  s[0][1] = __builtin_amdgcn_mfma_f32_16x16x32_bf16(a0, b1, z, 0, 0, 0);
  s[1][0] = __builtin_amdgcn_mfma_f32_16x16x32_bf16(a1, b0, z, 0, 0, 0);
  s[1][1] = __builtin_amdgcn_mfma_f32_16x16x32_bf16(a1, b1, z, 0, 0, 0);

  float* od = dout + (size_t)token * 1024;
  unsigned short* ob = wsp + (size_t)token * 1024;
#pragma unroll
  for (int rt = 0; rt < 2; ++rt) {
#pragma unroll
    for (int j = 0; j < 4; ++j) {
      const float v0 = s[rt][0][j], v1 = s[rt][1][j];
      float m = fmaxf(v0, v1);
#pragma unroll
      for (int msk = 1; msk < 16; msk <<= 1) m = fmaxf(m, __shfl_xor(m, msk, 64));
      const float e0 = __expf(v0 - m), e1 = __expf(v1 - m);
      float ssum = e0 + e1;
#pragma unroll
      for (int msk = 1; msk < 16; msk <<= 1) ssum += __shfl_xor(ssum, msk, 64);
      const float inv = 1.0f / ssum;
      const int h = rt * 16 + grp * 4 + j;
      if (PMODE == 0) {
        od[h * 32 + lo]      = e0 * inv;
        od[h * 32 + 16 + lo] = e1 * inv;
      } else {
        ob[h * 32 + lo]      = f2bf(e0 * inv);
        ob[h * 32 + 16 + lo] = f2bf(e1 * inv);
      }
    }
  }
}

extern "C" void kernel_launch(void* const* d_in, const int* in_sizes, int n_in,
                              void* d_out, int out_size, void* d_ws, size_t ws_size,
                              hipStream_t stream) {
  const float* query = (const float*)d_in[0];
  const float* key   = (const float*)d_in[1];
  const float* value = (const float*)d_in[2];
  const float* Wq    = (const float*)d_in[3];
  const float* bq    = (const float*)d_in[4];
  const float* Wk    = (const float*)d_in[5];
  const float* bk    = (const float*)d_in[6];
  const float* Wv    = (const float*)d_in[7];
  const float* bv    = (const float*)d_in[8];

  const int use_ws = (ws_size >= (size_t)32768 * 1024 * 2) ? 1 : 0;
  unsigned short* pbf = (unsigned short*)d_ws;

  gemm_kernel<0><<<dim3(2048), dim3(256), 0, stream>>>(query, Wq, bq, d_out, nullptr, 0);
  gemm_kernel<1><<<dim3(2048), dim3(256), 0, stream>>>(key,   Wk, bk, d_out, nullptr, 0);
  if (use_ws)
    attn_kernel<1><<<dim3(8192), dim3(256), 0, stream>>>((float*)d_out, pbf);
  else
    attn_kernel<0><<<dim3(8192), dim3(256), 0, stream>>>((float*)d_out, nullptr);
  gemm_kernel<2><<<dim3(2048), dim3(256), 0, stream>>>(value, Wv, bv, d_out, pbf, use_ws);
}

// Round 5
// 488.096 us; speedup vs baseline: 1.7742x; 1.7621x over previous
//
#include <hip/hip_runtime.h>
#include <hip/hip_bf16.h>

// B=4, S=8192 -> 32768 tokens; HID=1024; NH=DH=32.
// S1q: q=(query@Wq^T+bq)/32 -> bf16 @ dout_b[tok*2048 + n]
// S1k: k=(key@Wk^T+bk)      -> bf16 @ dout_b[tok*2048 + 1024 + n]
// S2 : per-token 32x32 scores + softmax over heads-t -> p (bf16 in d_ws if it
//      fits, else f32 in-place in d_out)
// S3 : v GEMM; epilogue out[idx] = p[idx] * (v+bv)
//
// GEMM: 128x128 tile, BK=32, 4 waves (64x64). COALESCED staging (8 lanes x
// 16B = 128B runs per row, round-1 map), bf16 subtiled LDS
// [row/16][kslot][row%16 ^ (kslot<<2)][16B] (0 read conflicts, 2-way writes).
// Pipeline: single raw s_barrier per K-step, lgkmcnt drain only; global
// loads stay in flight across barriers (issued 1 phase before use).

typedef __attribute__((ext_vector_type(8))) short bf16x8;
typedef __attribute__((ext_vector_type(4))) float f32x4;

#define HID 1024

__device__ __forceinline__ unsigned short f2bf(float f) {
  unsigned int u = __builtin_bit_cast(unsigned int, f);
  u += 0x7FFFu + ((u >> 16) & 1u);  // RTNE
  return (unsigned short)(u >> 16);
}
__device__ __forceinline__ float bf2f(unsigned short h) {
  unsigned int u = (unsigned int)h << 16;
  return __builtin_bit_cast(float, u);
}

// 4 f32 -> 4 bf16 (8B) via v_cvt_pk_bf16_f32
__device__ __forceinline__ uint2 cvt4(f32x4 a) {
  uint2 r;
  asm("v_cvt_pk_bf16_f32 %0, %1, %2" : "=v"(r.x) : "v"(a[0]), "v"(a[1]));
  asm("v_cvt_pk_bf16_f32 %0, %1, %2" : "=v"(r.y) : "v"(a[2]), "v"(a[3]));
  return r;
}

// out[m,n] = sum_k X[m,k]*W[n,k] + b[n]
template<int MODE>
__global__ __launch_bounds__(256, 4)
void gemm_kernel(const float* __restrict__ X, const float* __restrict__ W,
                 const float* __restrict__ bias, void* outp,
                 const unsigned short* __restrict__ pbf, int use_ws) {
  // XCD-chunked bijective swizzle: 2048 blocks = 8 chunks x 256; n fastest.
  const int bid = blockIdx.x;
  const int L = (bid & 7) * 256 + (bid >> 3);
  const int m0 = (L >> 3) * 128;
  const int n0 = (L & 7) * 128;
  const int tid = threadIdx.x;
  const int lane = tid & 63;
  const int wid = tid >> 6;
  const int wm = (wid >> 1) << 6;
  const int wn = (wid & 1) << 6;
  const int lo = lane & 15, grp = lane >> 4;

  // per buffer: A bf16 subtiled 8KB @0, B 8KB @8192.
  // addr(row,kslot) = (row>>4)*1024 + kslot*256 + ((row&15)^(kslot<<2))*16
  __shared__ __align__(16) unsigned char lds[2][16384];

  // staging (coalesced): srow = tid>>3 (8 lanes/row), skc = (tid&7)*4
  const int srow = tid >> 3;             // 0..31, rows srow+32*rr
  const int skc  = (tid & 7) << 2;       // f32 col
  const float* Ag = X + (size_t)(m0 + srow) * HID + skc;
  const float* Bg = W + (size_t)(n0 + srow) * HID + skc;
  const int slot = skc >> 3;             // k-slot (8 bf16 per slot)
  const int off8 = (skc & 4) << 1;       // byte half within 16B block
  const int r15x = (srow & 15) ^ (slot << 2);
  const int wb0 = (srow >> 4) * 1024 + slot * 256 + r15x * 16 + off8;

  f32x4 la[4], lb[4];
  auto gload = [&](int k0) {
#pragma unroll
    for (int rr = 0; rr < 4; ++rr) {
      la[rr] = *(const f32x4*)(Ag + (size_t)(rr * 32) * HID + k0);
      lb[rr] = *(const f32x4*)(Bg + (size_t)(rr * 32) * HID + k0);
    }
  };
  auto cvtwrite = [&](int b) {
#pragma unroll
    for (int rr = 0; rr < 4; ++rr) {
      *(uint2*)&lds[b][wb0 + rr * 2048]        = cvt4(la[rr]);
      *(uint2*)&lds[b][8192 + wb0 + rr * 2048] = cvt4(lb[rr]);
    }
  };

  f32x4 acc[4][4] = {};
  const int rbA = (wm >> 4) * 1024 + grp * 256 + ((lo ^ (grp << 2)) << 4);
  const int rbB = 8192 + (wn >> 4) * 1024 + grp * 256 + ((lo ^ (grp << 2)) << 4);
  auto compute = [&](int b) {
    bf16x8 af[4], bfm[4];
#pragma unroll
    for (int f = 0; f < 4; ++f) {
      af[f]  = *(const bf16x8*)&lds[b][rbA + f * 1024];
      bfm[f] = *(const bf16x8*)&lds[b][rbB + f * 1024];
    }
#pragma unroll
    for (int fm = 0; fm < 4; ++fm)
#pragma unroll
      for (int fn = 0; fn < 4; ++fn)
        acc[fm][fn] = __builtin_amdgcn_mfma_f32_16x16x32_bf16(
            af[fm], bfm[fn], acc[fm][fn], 0, 0, 0);
  };

  // Prologue: tile0 staged, tile1 left in flight across the barrier.
  gload(0);
  cvtwrite(0);
  gload(32);
  __builtin_amdgcn_sched_barrier(0);
  asm volatile("s_waitcnt lgkmcnt(0)" ::: "memory");
  __builtin_amdgcn_s_barrier();
  __builtin_amdgcn_sched_barrier(0);

#pragma unroll 1
  for (int kt = 0; kt < 32; ++kt) {
    compute(kt & 1);                       // ds_read + MFMA on current buffer
    if (kt < 31) {
      cvtwrite((kt + 1) & 1);              // vmcnt wait lands here (1 phase late)
      if (kt < 30) gload((kt + 2) * 32);   // issue next; stays in flight
    }
    __builtin_amdgcn_sched_barrier(0);
    asm volatile("s_waitcnt lgkmcnt(0)" ::: "memory");  // ds ops drained only
    __builtin_amdgcn_s_barrier();          // raw: vmem loads NOT drained
    __builtin_amdgcn_sched_barrier(0);
  }

  // Epilogue. C layout: col=lane&15, row=(lane>>4)*4+j (m89-verified).
  unsigned char* eb = &lds[0][0];  // 32KB staging
  const unsigned char* ebc = eb;
  if (MODE == 2) {
    float* of = (float*)outp;
#pragma unroll
    for (int fm = 0; fm < 4; ++fm) {
      const int row = m0 + wm + fm * 16 + grp * 4;
#pragma unroll
      for (int fn = 0; fn < 4; ++fn) {
        const int col = n0 + wn + fn * 16 + lo;
        const float bc = bias[col];
#pragma unroll
        for (int j = 0; j < 4; ++j) {
          const size_t idx = (size_t)(row + j) * 1024 + col;
          const float p = use_ws ? bf2f(pbf[idx]) : of[idx];
          of[idx] = p * (acc[fm][fn][j] + bc);
        }
      }
    }
  } else {
    const float scale = (MODE == 0) ? 0.03125f : 1.0f;
#pragma unroll
    for (int fm = 0; fm < 4; ++fm) {
#pragma unroll
      for (int fn = 0; fn < 4; ++fn) {
        const int colL = wn + fn * 16 + lo;
        const float bc = bias[n0 + colL];
#pragma unroll
        for (int j = 0; j < 4; ++j) {
          const int rowL = wm + fm * 16 + grp * 4 + j;
          const int byte = rowL * 256 + ((colL * 2) ^ ((rowL & 7) << 5));
          *(unsigned short*)&eb[byte] = f2bf((acc[fm][fn][j] + bc) * scale);
        }
      }
    }
    __syncthreads();
    unsigned short* ob = (unsigned short*)outp;
    const int half = (MODE == 1) ? 1024 : 0;
#pragma unroll
    for (int p = 0; p < 8; ++p) {
      const int r = p * 16 + (tid >> 4);
      const int c0 = (tid & 15) * 8;
      const uint4 v = *(const uint4*)&ebc[r * 256 + ((c0 * 2) ^ ((r & 7) << 5))];
      *(uint4*)&ob[(size_t)(m0 + r) * 2048 + half + n0 + c0] = v;
    }
  }
}

// S2: one wave per token. 32x32 scores via 4 MFMA, softmax over t (cols).
// PMODE 0: write f32 p in-place over the token's q/k region in d_out.
// PMODE 1: write bf16 p to d_ws[tok*1024 + h*32 + t].
template<int PMODE>
__global__ __launch_bounds__(256)
void attn_kernel(float* __restrict__ dout, unsigned short* __restrict__ wsp) {
  const int wid = threadIdx.x >> 6;
  const int lane = threadIdx.x & 63;
  const int token = blockIdx.x * 4 + wid;
  const int lo = lane & 15, grp = lane >> 4;
  const unsigned short* qk = (const unsigned short*)dout + (size_t)token * 2048;
  const int base = lo * 32 + grp * 8;

  bf16x8 a0 = *(const bf16x8*)(qk + base);
  bf16x8 a1 = *(const bf16x8*)(qk + 512 + base);
  bf16x8 b0 = *(const bf16x8*)(qk + 1024 + base);
  bf16x8 b1 = *(const bf16x8*)(qk + 1536 + base);
  asm volatile("s_waitcnt vmcnt(0)" ::: "memory");  // before in-place overwrite

  const f32x4 z = {0.f, 0.f, 0.f, 0.f};
  f32x4 s[2][2];
  s[0][0] = __builtin_amdgcn_mfma_f32_16x16x32_bf16(a0, b0, z, 0, 0, 0);
  s[0][1] = __builtin_amdgcn_mfma_f32_16x16x32_bf16(a0, b1, z, 0, 0, 0);
  s[1][0] = __builtin_amdgcn_mfma_f32_16x16x32_bf16(a1, b0, z, 0, 0, 0);
  s[1][1] = __builtin_amdgcn_mfma_f32_16x16x32_bf16(a1, b1, z, 0, 0, 0);

  float* od = dout + (size_t)token * 1024;
  unsigned short* ob = wsp + (size_t)token * 1024;
#pragma unroll
  for (int rt = 0; rt < 2; ++rt) {
#pragma unroll
    for (int j = 0; j < 4; ++j) {
      const float v0 = s[rt][0][j], v1 = s[rt][1][j];
      float m = fmaxf(v0, v1);
#pragma unroll
      for (int msk = 1; msk < 16; msk <<= 1) m = fmaxf(m, __shfl_xor(m, msk, 64));
      const float e0 = __expf(v0 - m), e1 = __expf(v1 - m);
      float ssum = e0 + e1;
#pragma unroll
      for (int msk = 1; msk < 16; msk <<= 1) ssum += __shfl_xor(ssum, msk, 64);
      const float inv = 1.0f / ssum;
      const int h = rt * 16 + grp * 4 + j;
      if (PMODE == 0) {
        od[h * 32 + lo]      = e0 * inv;
        od[h * 32 + 16 + lo] = e1 * inv;
      } else {
        ob[h * 32 + lo]      = f2bf(e0 * inv);
        ob[h * 32 + 16 + lo] = f2bf(e1 * inv);
      }
    }
  }
}

extern "C" void kernel_launch(void* const* d_in, const int* in_sizes, int n_in,
                              void* d_out, int out_size, void* d_ws, size_t ws_size,
                              hipStream_t stream) {
  const float* query = (const float*)d_in[0];
  const float* key   = (const float*)d_in[1];
  const float* value = (const float*)d_in[2];
  const float* Wq    = (const float*)d_in[3];
  const float* bq    = (const float*)d_in[4];
  const float* Wk    = (const float*)d_in[5];
  const float* bk    = (const float*)d_in[6];
  const float* Wv    = (const float*)d_in[7];
  const float* bv    = (const float*)d_in[8];

  const int use_ws = (ws_size >= (size_t)32768 * 1024 * 2) ? 1 : 0;
  unsigned short* pbf = (unsigned short*)d_ws;

  gemm_kernel<0><<<dim3(2048), dim3(256), 0, stream>>>(query, Wq, bq, d_out, nullptr, 0);
  gemm_kernel<1><<<dim3(2048), dim3(256), 0, stream>>>(key,   Wk, bk, d_out, nullptr, 0);
  if (use_ws)
    attn_kernel<1><<<dim3(8192), dim3(256), 0, stream>>>((float*)d_out, pbf);
  else
    attn_kernel<0><<<dim3(8192), dim3(256), 0, stream>>>((float*)d_out, nullptr);
  gemm_kernel<2><<<dim3(2048), dim3(256), 0, stream>>>(value, Wv, bv, d_out, pbf, use_ws);
}